// Round 3
// baseline (322.981 us; speedup 1.0000x reference)
//
#include <hip/hip_runtime.h>
#include <stdint.h>

#define N_NODES_C 20000
#define N_EDGES_C 320000
#define NUM_RELS_C 16
#define FEAT_C 256
#define KDIM 4096   // NUM_RELS_C * FEAT_C

typedef __bf16 bf16_t;
typedef __bf16 bf16x8 __attribute__((ext_vector_type(8)));
typedef float f32x4 __attribute__((ext_vector_type(4)));

__device__ __forceinline__ void async_load16(const void* g, void* l) {
  __builtin_amdgcn_global_load_lds(
      (__attribute__((address_space(1))) void*)const_cast<void*>(g),
      (__attribute__((address_space(3))) void*)l, 16, 0, 0);
}

// ---- W [r][in][out] fp32 -> Wt2 [out][r*256+in] bf16, LDS tile transpose ----
__global__ void cvt_w2_kernel(const float* __restrict__ W, bf16_t* __restrict__ Wt2) {
  __shared__ float t[32][33];
  int r = blockIdx.z, i0 = blockIdx.x << 5, o0 = blockIdx.y << 5;
  int a = threadIdx.x >> 5;   // 0..7
  int b = threadIdx.x & 31;
#pragma unroll
  for (int k = 0; k < 4; ++k) {
    int i = a + (k << 3);
    t[i][b] = W[(r << 16) + ((i0 + i) << 8) + o0 + b];
  }
  __syncthreads();
#pragma unroll
  for (int k = 0; k < 4; ++k) {
    int o = a + (k << 3);
    Wt2[((size_t)(o0 + o) << 12) + (r << 8) + i0 + b] = (bf16_t)t[b][o];
  }
}

// ---- dst histogram ----
__global__ void hist_dst_kernel(const int* __restrict__ dst, int* __restrict__ dcur) {
  int e = blockIdx.x * blockDim.x + threadIdx.x;
  if (e < N_EDGES_C) atomicAdd(&dcur[dst[e]], 1);
}

// ---- single-block exclusive scan -> dstart[20001]; dcur becomes cursor ----
__global__ void scan_dst_kernel(int* __restrict__ dcur, int* __restrict__ dstart) {
  __shared__ int part[256];
  const int CH = 79;
  int t = threadIdx.x;
  int base = t * CH;
  int sum = 0;
  for (int i = 0; i < CH; ++i) {
    int idx = base + i;
    if (idx < N_NODES_C) sum += dcur[idx];
  }
  part[t] = sum;
  __syncthreads();
  if (t == 0) {
    int run = 0;
    for (int i = 0; i < 256; ++i) { int v = part[i]; part[i] = run; run += v; }
  }
  __syncthreads();
  int run = part[t];
  for (int i = 0; i < CH; ++i) {
    int idx = base + i;
    if (idx < N_NODES_C) {
      int c = dcur[idx];
      dstart[idx] = run;
      dcur[idx] = run;
      run += c;
    }
  }
  if (t == 0) dstart[N_NODES_C] = N_EDGES_C;
}

// ---- bucket edges by dst: packed (src | rel<<16) + norm ----
__global__ void bucket_dst_kernel(const int* __restrict__ dst, const int* __restrict__ src,
                                  const int* __restrict__ rel, const float* __restrict__ norm,
                                  int* __restrict__ dcur, int* __restrict__ bkt_sr,
                                  float* __restrict__ bkt_nm) {
  int e = blockIdx.x * blockDim.x + threadIdx.x;
  if (e < N_EDGES_C) {
    int pos = atomicAdd(&dcur[dst[e]], 1);
    bkt_sr[pos] = src[e] | (rel[e] << 16);
    bkt_nm[pos] = norm[e];
  }
}

// ---- G build: one block per dst. acc[r][tid] in LDS (fp32), no barriers needed
// (each thread owns column tid). h reads are 4B/lane coalesced, cache-resident. ----
__global__ __launch_bounds__(256) void gbuild_kernel(
    const float* __restrict__ h, const int* __restrict__ dstart,
    const int* __restrict__ bkt_sr, const float* __restrict__ bkt_nm,
    bf16_t* __restrict__ G) {
  __shared__ float acc[NUM_RELS_C][FEAT_C];   // 16 KB
  int d = blockIdx.x;
  int tid = threadIdx.x;
#pragma unroll
  for (int r = 0; r < NUM_RELS_C; ++r) acc[r][tid] = 0.f;
  int p0 = dstart[d], p1 = dstart[d + 1];
  int p = p0;
  for (; p + 1 < p1; p += 2) {
    int sr0 = bkt_sr[p];
    int sr1 = bkt_sr[p + 1];
    float nm0 = bkt_nm[p];
    float nm1 = bkt_nm[p + 1];
    float v0 = h[((size_t)(sr0 & 0xFFFF) << 8) + tid];
    float v1 = h[((size_t)(sr1 & 0xFFFF) << 8) + tid];
    acc[sr0 >> 16][tid] += nm0 * v0;
    acc[sr1 >> 16][tid] += nm1 * v1;
  }
  if (p < p1) {
    int sr0 = bkt_sr[p];
    float nm0 = bkt_nm[p];
    float v0 = h[((size_t)(sr0 & 0xFFFF) << 8) + tid];
    acc[sr0 >> 16][tid] += nm0 * v0;
  }
  bf16_t* g = G + ((size_t)d << 12);
#pragma unroll
  for (int r = 0; r < NUM_RELS_C; ++r) g[(r << 8) + tid] = (bf16_t)acc[r][tid];
}

// ---- GEMM: out[20000,256] = G[20000,4096] @ Wt2^T. 128x128 tile, BK=64,
// 64 k-iters, 32 MFMA per barrier pair. Swizzle identical to R2's verified
// 0-conflict pattern (64B half-rows, chunk = lq ^ ((lr>>1)&3)). ----
__global__ __launch_bounds__(256) void gemm_kernel(
    const bf16_t* __restrict__ G, const bf16_t* __restrict__ Wt2,
    float* __restrict__ out) {
  int m0 = blockIdx.x * 128;
  int n0 = blockIdx.y * 128;
  __shared__ bf16_t Asm[128 * 64];   // 16 KB
  __shared__ bf16_t Bsm[128 * 64];   // 16 KB
  int tid = threadIdx.x;

  const char* gA[4];
  const char* gB[4];
  char* lA[4];
  char* lB[4];
#pragma unroll
  for (int l = 0; l < 4; ++l) {
    int idx = l * 256 + tid;          // 16B-chunk index, 0..1023
    int row = idx >> 3;               // 0..127
    int half = (idx >> 2) & 1;
    int pq = idx & 3;
    int lc16 = half * 4 + (pq ^ ((row >> 1) & 3));   // logical 16B chunk in 128B k-slab
    int grA = m0 + row; if (grA > N_NODES_C - 1) grA = N_NODES_C - 1;
    gA[l] = (const char*)G + ((size_t)grA << 13) + lc16 * 16;
    gB[l] = (const char*)Wt2 + ((size_t)(n0 + row) << 13) + lc16 * 16;
    lA[l] = (char*)Asm + idx * 16;    // = wave-uniform base + lane*16
    lB[l] = (char*)Bsm + idx * 16;
  }

  int lane = tid & 63;
  int lq = lane >> 4;
  int lr = lane & 15;
  int wave = tid >> 6;
  int wm = (wave >> 1) * 64;
  int wn = (wave & 1) * 64;
  int cq = (lq ^ ((lr >> 1) & 3)) * 8;   // element offset of lane's 16B chunk

  f32x4 acc[4][4] = {};

  for (int kk = 0; kk < 64; ++kk) {
    int kb = kk * 128;   // 64 bf16 = 128 B per K tile
#pragma unroll
    for (int l = 0; l < 4; ++l) async_load16(gA[l] + kb, lA[l]);
#pragma unroll
    for (int l = 0; l < 4; ++l) async_load16(gB[l] + kb, lB[l]);
    __syncthreads();
    bf16x8 af[2][4], bfr[2][4];
#pragma unroll
    for (int inner = 0; inner < 2; ++inner)
#pragma unroll
      for (int mt = 0; mt < 4; ++mt) {
        int row = wm + mt * 16 + lr;
        af[inner][mt] = *(const bf16x8*)&Asm[row * 64 + inner * 32 + cq];
      }
#pragma unroll
    for (int inner = 0; inner < 2; ++inner)
#pragma unroll
      for (int nt = 0; nt < 4; ++nt) {
        int row = wn + nt * 16 + lr;
        bfr[inner][nt] = *(const bf16x8*)&Bsm[row * 64 + inner * 32 + cq];
      }
#pragma unroll
    for (int inner = 0; inner < 2; ++inner)
#pragma unroll
      for (int mt = 0; mt < 4; ++mt)
#pragma unroll
        for (int nt = 0; nt < 4; ++nt)
          acc[mt][nt] = __builtin_amdgcn_mfma_f32_16x16x32_bf16(af[inner][mt], bfr[inner][nt], acc[mt][nt], 0, 0, 0);
    __syncthreads();
  }

  // Epilogue: C/D map col=lane&15, row=quad*4+reg. Direct fp32 store, no atomics.
#pragma unroll
  for (int mt = 0; mt < 4; ++mt) {
#pragma unroll
    for (int rg = 0; rg < 4; ++rg) {
      int row = m0 + wm + mt * 16 + lq * 4 + rg;
      if (row < N_NODES_C) {
#pragma unroll
        for (int nt = 0; nt < 4; ++nt)
          out[((size_t)row << 8) + n0 + wn + nt * 16 + lr] = acc[mt][nt][rg];
      }
    }
  }
}

extern "C" void kernel_launch(void* const* d_in, const int* in_sizes, int n_in,
                              void* d_out, int out_size, void* d_ws, size_t ws_size,
                              hipStream_t stream) {
  const float* h    = (const float*)d_in[0];
  const float* W    = (const float*)d_in[1];
  const float* norm = (const float*)d_in[2];
  const int*   src  = (const int*)d_in[3];
  const int*   dst  = (const int*)d_in[4];
  const int*   rel  = (const int*)d_in[5];
  float* out = (float*)d_out;

  char* ws = (char*)d_ws;
  bf16_t* G     = (bf16_t*)ws;                         // 163,840,000 B
  bf16_t* Wt2   = (bf16_t*)(ws + 163840000);           //   2,097,152 B
  int* dstart   = (int*)(ws + 165937152);              //      80,016 B
  int* dcur     = (int*)(ws + 166017168);              //      80,000 B
  int* bkt_sr   = (int*)(ws + 166097168);              //   1,280,000 B
  float* bkt_nm = (float*)(ws + 167377168);            //   1,280,000 B (end ~168.7 MB)

  hipMemsetAsync(dcur, 0, N_NODES_C * sizeof(int), stream);
  cvt_w2_kernel<<<dim3(8, 8, NUM_RELS_C), 256, 0, stream>>>(W, Wt2);
  hist_dst_kernel<<<1250, 256, 0, stream>>>(dst, dcur);
  scan_dst_kernel<<<1, 256, 0, stream>>>(dcur, dstart);
  bucket_dst_kernel<<<1250, 256, 0, stream>>>(dst, src, rel, norm, dcur, bkt_sr, bkt_nm);
  gbuild_kernel<<<N_NODES_C, 256, 0, stream>>>(h, dstart, bkt_sr, bkt_nm, G);
  gemm_kernel<<<dim3(157, 2), 256, 0, stream>>>(G, Wt2, out);
}